// Round 2
// baseline (8918.582 us; speedup 1.0000x reference)
//
#include <hip/hip_runtime.h>
#include <hip/hip_bf16.h>

// All reference tensors are float32 (per reference source). Internal compute fp32.

#define BSZ 8192
#define TM 64
#define TN 64
#define BK 32
#define PAD 68   // leading-dim pad: rows 272B apart (16B-aligned), breaks 32-bank stride

// A-element fetch modes:
//  0: concat(x [B,128], z [B,32])      K=160
//  1: fp32 buffer [B,256]              K=256
//  2: concat(buf [B,256], z [B,32])    K=288
__device__ __forceinline__ float loadA(int amode, const float* Af, const float* Ax,
                                       const float* Az, int b, int k) {
    if (amode == 0)
        return (k < 128) ? Ax[b * 128 + k] : Az[b * 32 + (k - 128)];
    if (amode == 1)
        return Af[b * 256 + k];
    return (k < 256) ? Af[b * 256 + k] : Az[b * 32 + (k - 256)];
}

// out[M,N] = act( sum_e coef[b,e] * (A @ W_e) + coef @ bias ), EXP=1 -> plain GEMM
template <int EXP>
__global__ __launch_bounds__(256) void moe_gemm(
    int amode, const float* __restrict__ Af, const float* __restrict__ Ax,
    const float* __restrict__ Az, const float* __restrict__ W,
    const float* __restrict__ bias, const float* __restrict__ coef,
    int K, int N, int act, float* __restrict__ out) {
    __shared__ float As[BK][PAD];
    __shared__ float Ws[BK][PAD];

    const int tid  = threadIdx.x;
    const int row0 = blockIdx.x * TM;
    const int col0 = blockIdx.y * TN;
    const int ty   = tid >> 4;   // 0..15 -> 4 rows each
    const int tx   = tid & 15;   // 0..15 -> 4 cols each

    // Per-row expert coefficients in registers (static indexing only).
    float cf[4][EXP];
#pragma unroll
    for (int i = 0; i < 4; ++i)
#pragma unroll
        for (int e = 0; e < EXP; ++e)
            cf[i][e] = (EXP == 1) ? 1.0f : coef[(row0 + ty * 4 + i) * 8 + e];

    float acc[4][4] = {};

    for (int kc = 0; kc < K; kc += BK) {
        __syncthreads();  // prior compute done before As overwrite
        // Stage A chunk: 32(k) x 64(m), 8 elems/thread.
#pragma unroll
        for (int r = 0; r < (BK * TM) / 256; ++r) {
            int idx = r * 256 + tid;
            int m = idx >> 5, kk = idx & 31;
            As[kk][m] = loadA(amode, Af, Ax, Az, row0 + m, kc + kk);
        }
#pragma unroll
        for (int e = 0; e < EXP; ++e) {
            const float* We = W + ((size_t)e * K + kc) * N;
            __syncthreads();  // prior reads of Ws (and As stage for e==0) complete
#pragma unroll
            for (int r = 0; r < (BK * TN) / 256; ++r) {
                int idx = r * 256 + tid;
                int kk = idx >> 6, n = idx & 63;
                int gn = col0 + n;
                Ws[kk][n] = (gn < N) ? We[kk * N + gn] : 0.0f;
            }
            __syncthreads();
            float acce[4][4] = {};
#pragma unroll
            for (int kk = 0; kk < BK; ++kk) {
                const float4 a4 = *(const float4*)&As[kk][ty * 4];
                const float4 w4 = *(const float4*)&Ws[kk][tx * 4];
                const float a[4] = {a4.x, a4.y, a4.z, a4.w};
                const float w[4] = {w4.x, w4.y, w4.z, w4.w};
#pragma unroll
                for (int i = 0; i < 4; ++i)
#pragma unroll
                    for (int j = 0; j < 4; ++j) acce[i][j] += a[i] * w[j];
            }
#pragma unroll
            for (int i = 0; i < 4; ++i) {
                const float c = cf[i][e];
#pragma unroll
                for (int j = 0; j < 4; ++j) acc[i][j] += c * acce[i][j];
            }
        }
    }

    // Epilogue: coef-mixed bias, activation, store.
#pragma unroll
    for (int e = 0; e < EXP; ++e) {
#pragma unroll
        for (int j = 0; j < 4; ++j) {
            int gn = col0 + tx * 4 + j;
            float bv = (gn < N) ? bias[e * N + gn] : 0.0f;
#pragma unroll
            for (int i = 0; i < 4; ++i) acc[i][j] += cf[i][e] * bv;
        }
    }
#pragma unroll
    for (int i = 0; i < 4; ++i) {
        int gm = row0 + ty * 4 + i;
#pragma unroll
        for (int j = 0; j < 4; ++j) {
            int gn = col0 + tx * 4 + j;
            if (gn < N) {
                float v = acc[i][j];
                if (act) v = (v > 0.0f) ? v : expm1f(v);  // ELU(alpha=1)
                out[(size_t)gm * N + gn] = v;
            }
        }
    }
}

__global__ __launch_bounds__(256) void softmax8_kernel(const float* __restrict__ logits,
                                                       float* __restrict__ coef) {
    int b = blockIdx.x * 256 + threadIdx.x;
    if (b >= BSZ) return;
    float v[8];
    float m = -1e30f;
#pragma unroll
    for (int e = 0; e < 8; ++e) {
        v[e] = logits[b * 8 + e];
        m = fmaxf(m, v[e]);
    }
    float s = 0.0f;
#pragma unroll
    for (int e = 0; e < 8; ++e) {
        v[e] = expf(v[e] - m);
        s += v[e];
    }
    float inv = 1.0f / s;
#pragma unroll
    for (int e = 0; e < 8; ++e) coef[b * 8 + e] = v[e] * inv;
}

extern "C" void kernel_launch(void* const* d_in, const int* in_sizes, int n_in,
                              void* d_out, int out_size, void* d_ws, size_t ws_size,
                              hipStream_t stream) {
    const float* x   = (const float*)d_in[0];
    const float* z   = (const float*)d_in[1];
    const float* gw0 = (const float*)d_in[2];
    const float* gb0 = (const float*)d_in[3];
    const float* gw1 = (const float*)d_in[4];
    const float* gb1 = (const float*)d_in[5];
    const float* gw2 = (const float*)d_in[6];
    const float* gb2 = (const float*)d_in[7];
    const float* gw3 = (const float*)d_in[8];
    const float* gb3 = (const float*)d_in[9];
    const float* w0  = (const float*)d_in[10];
    const float* b0  = (const float*)d_in[11];
    const float* w1  = (const float*)d_in[12];
    const float* b1  = (const float*)d_in[13];
    const float* w2  = (const float*)d_in[14];
    const float* b2  = (const float*)d_in[15];

    float* ws     = (float*)d_ws;
    float* bufA   = ws;                       // 8192*256 fp32
    float* bufB   = ws + BSZ * 256;           // 8192*256 fp32
    float* logits = ws + 2 * BSZ * 256;       // 8192*8
    float* coef   = logits + BSZ * 8;         // 8192*8
    float* out    = (float*)d_out;

    dim3 blk(256);
    // Gating MLP
    moe_gemm<1><<<dim3(BSZ / TM, 4), blk, 0, stream>>>(0, nullptr, x, z, gw0, gb0,
                                                       nullptr, 160, 256, 1, bufA);
    moe_gemm<1><<<dim3(BSZ / TM, 4), blk, 0, stream>>>(1, bufA, nullptr, nullptr, gw1, gb1,
                                                       nullptr, 256, 256, 1, bufB);
    moe_gemm<1><<<dim3(BSZ / TM, 4), blk, 0, stream>>>(1, bufB, nullptr, nullptr, gw2, gb2,
                                                       nullptr, 256, 256, 1, bufA);
    moe_gemm<1><<<dim3(BSZ / TM, 1), blk, 0, stream>>>(1, bufA, nullptr, nullptr, gw3, gb3,
                                                       nullptr, 256, 8, 0, logits);
    softmax8_kernel<<<dim3(BSZ / 256), blk, 0, stream>>>(logits, coef);
    // Expert layers (coef-mixed)
    moe_gemm<8><<<dim3(BSZ / TM, 4), blk, 0, stream>>>(0, nullptr, x, z, w0, b0,
                                                       coef, 160, 256, 1, bufB);
    moe_gemm<8><<<dim3(BSZ / TM, 4), blk, 0, stream>>>(2, bufB, nullptr, z, w1, b1,
                                                       coef, 288, 256, 1, bufA);
    moe_gemm<8><<<dim3(BSZ / TM, 2), blk, 0, stream>>>(2, bufA, nullptr, z, w2, b2,
                                                       coef, 288, 128, 0, out);
}

// Round 3
// 276.017 us; speedup vs baseline: 32.3117x; 32.3117x over previous
//
#include <hip/hip_runtime.h>
#include <hip/hip_bf16.h>

typedef __hip_bfloat16 bf16;
typedef __attribute__((ext_vector_type(8))) short short8;    // 8 bf16 (4 VGPRs)
typedef __attribute__((ext_vector_type(4))) float float4v;
typedef __attribute__((ext_vector_type(2))) float float2v;
typedef __attribute__((ext_vector_type(4))) unsigned int uint4v;

#define BSZ 8192
#define LSTR 40  // LDS row stride in bf16 elems: 80 B, 16B-aligned, <=2-way bank conflicts

__device__ __forceinline__ void split_bf16(float v, bf16& h, bf16& l) {
    h = __float2bfloat16(v);
    l = __float2bfloat16(v - __bfloat162float(h));
}

// D[64m x 64n block] = act( sum_e coef[b,e]*(A @ W_e) + coef @ bias )
// A given as hi/lo bf16 [B x lda]; W given as hi/lo bf16 transposed [e][Npad][K].
// fp32-equivalent precision via 3-term hi/lo MFMA: Ah*Wh + Al*Wh + Ah*Wl.
// MODE 0: ELU + hi/lo bf16 store (stride ldo). MODE 1: plain fp32 store.
template <int EXP, int MODE>
__global__ __launch_bounds__(256, 1) void mfma_moe(
    const bf16* __restrict__ Ah, const bf16* __restrict__ Al, int lda,
    const bf16* __restrict__ Wh, const bf16* __restrict__ Wl,
    const float* __restrict__ bias, int biasN, const float* __restrict__ coef,
    int K, int Nvalid, bf16* __restrict__ Oh, bf16* __restrict__ Ol,
    float* __restrict__ Of, int ldo) {
    // LDS: Ah[64][40], Al[64][40], Bh[EXP][64][40], Bl[EXP][64][40]
    __shared__ __align__(16) unsigned short sMem[(2 + 2 * EXP) * 64 * LSTR];
    __shared__ float sCf[EXP == 8 ? 512 : 8];

    const int tid  = threadIdx.x;
    const int row0 = blockIdx.x * 64;
    const int col0 = blockIdx.y * 64;
    const int Npad = gridDim.y * 64;
    const int lane = tid & 63, wv = tid >> 6;
    const int l15  = lane & 15, quad = lane >> 4;
    const int sm   = tid >> 2;        // staging row (m or n), 0..63
    const int sk   = (tid & 3) * 8;   // staging k offset (8 bf16 = 16 B)

    if (EXP == 8) {  // stage coef tile [64 rows x 8 experts]
        *(float2v*)&sCf[tid * 2] = *(const float2v*)&coef[(size_t)row0 * 8 + tid * 2];
    }

    float4v acc[EXP][4];
#pragma unroll
    for (int e = 0; e < EXP; ++e)
#pragma unroll
        for (int mt = 0; mt < 4; ++mt) acc[e][mt] = (float4v){0.f, 0.f, 0.f, 0.f};

    for (int kc = 0; kc < K; kc += 32) {
        __syncthreads();  // prior chunk's ds_reads drained (and sCf visible)
        {   // stage A hi/lo: 64 m x 32 k
            const size_t go = (size_t)(row0 + sm) * lda + kc + sk;
            *(uint4v*)&sMem[sm * LSTR + sk]              = *(const uint4v*)&Ah[go];
            *(uint4v*)&sMem[2560 + sm * LSTR + sk]       = *(const uint4v*)&Al[go];
        }
#pragma unroll
        for (int e = 0; e < EXP; ++e) {  // stage B hi/lo: [n][k] rows, pre-transposed global
            const size_t go = ((size_t)e * Npad + col0 + sm) * K + kc + sk;
            *(uint4v*)&sMem[5120 + (e * 64 + sm) * LSTR + sk]              = *(const uint4v*)&Wh[go];
            *(uint4v*)&sMem[5120 + EXP * 2560 + (e * 64 + sm) * LSTR + sk] = *(const uint4v*)&Wl[go];
        }
        __syncthreads();

        // A fragments: m = mt*16 + l15, k = quad*8 + j   (hoisted across experts)
        short8 ah[4], al[4];
#pragma unroll
        for (int mt = 0; mt < 4; ++mt) {
            const int ao = (mt * 16 + l15) * LSTR + quad * 8;
            ah[mt] = *(const short8*)&sMem[ao];
            al[mt] = *(const short8*)&sMem[2560 + ao];
        }
#pragma unroll
        for (int e = 0; e < EXP; ++e) {
            const int bo = 5120 + (e * 64 + wv * 16 + l15) * LSTR + quad * 8;
            short8 bh = *(const short8*)&sMem[bo];
            short8 bl = *(const short8*)&sMem[bo + EXP * 2560];
#pragma unroll
            for (int mt = 0; mt < 4; ++mt) {
                acc[e][mt] = __builtin_amdgcn_mfma_f32_16x16x32_bf16(ah[mt], bh, acc[e][mt], 0, 0, 0);
                acc[e][mt] = __builtin_amdgcn_mfma_f32_16x16x32_bf16(al[mt], bh, acc[e][mt], 0, 0, 0);
                acc[e][mt] = __builtin_amdgcn_mfma_f32_16x16x32_bf16(ah[mt], bl, acc[e][mt], 0, 0, 0);
            }
        }
    }

    // Epilogue. C/D layout: col = l15, row = quad*4 + reg (within 16x16 tile mt).
    const int col = col0 + wv * 16 + l15;
    const bool cok = col < Nvalid;
    float bv[EXP];
#pragma unroll
    for (int e = 0; e < EXP; ++e) bv[e] = cok ? bias[e * biasN + col] : 0.f;

#pragma unroll
    for (int mt = 0; mt < 4; ++mt) {
#pragma unroll
        for (int r = 0; r < 4; ++r) {
            const int rl = mt * 16 + quad * 4 + r;
            float val;
            if (EXP == 1) {
                val = acc[0][mt][r] + bv[0];
            } else {
                val = 0.f;
#pragma unroll
                for (int e = 0; e < EXP; ++e) val += sCf[rl * 8 + e] * (acc[e][mt][r] + bv[e]);
            }
            if (cok) {
                const size_t o = (size_t)(row0 + rl) * ldo + col;
                if (MODE == 0) {
                    val = (val > 0.f) ? val : expm1f(val);  // ELU
                    bf16 h, l;
                    split_bf16(val, h, l);
                    Oh[o] = h; Ol[o] = l;
                } else {
                    Of[o] = val;
                }
            }
        }
    }
}

// Build A0 (concat x,z -> hi/lo, [B x 160]) and fill z-cols 256..287 of P and Q.
__global__ __launch_bounds__(256) void conv_inputs(
    const float* __restrict__ x, const float* __restrict__ z,
    bf16* __restrict__ A0h, bf16* __restrict__ A0l,
    bf16* __restrict__ Ph, bf16* __restrict__ Pl,
    bf16* __restrict__ Qh, bf16* __restrict__ Ql) {
    int idx = blockIdx.x * 256 + threadIdx.x;  // BSZ*192 total
    int b = idx / 192, c = idx % 192;
    float v = (c < 128) ? x[(size_t)b * 128 + c] : z[(size_t)b * 32 + ((c - 128) & 31)];
    bf16 h, l;
    split_bf16(v, h, l);
    if (c < 160) {
        size_t o = (size_t)b * 160 + c;
        A0h[o] = h; A0l[o] = l;
    } else {
        size_t o = (size_t)b * 288 + 256 + (c - 160);
        Ph[o] = h; Pl[o] = l;
        Qh[o] = h; Ql[o] = l;
    }
}

// W [E][K][N] fp32 -> transposed hi/lo bf16 [E][Npad][K] (zero-padded cols n>=N).
__global__ __launch_bounds__(256) void conv_w(const float* __restrict__ W,
                                              bf16* __restrict__ Dh, bf16* __restrict__ Dl,
                                              int E, int K, int N, int Npad) {
    int idx = blockIdx.x * 256 + threadIdx.x;
    if (idx >= E * Npad * K) return;
    int k = idx % K, t = idx / K;
    int n = t % Npad, e = t / Npad;
    float v = (n < N) ? W[((size_t)e * K + k) * N + n] : 0.f;
    bf16 h, l;
    split_bf16(v, h, l);
    Dh[idx] = h; Dl[idx] = l;
}

__global__ __launch_bounds__(256) void softmax8_kernel(const float* __restrict__ logits,
                                                       float* __restrict__ coef) {
    int b = blockIdx.x * 256 + threadIdx.x;
    if (b >= BSZ) return;
    float v[8], m = -1e30f;
#pragma unroll
    for (int e = 0; e < 8; ++e) { v[e] = logits[b * 8 + e]; m = fmaxf(m, v[e]); }
    float s = 0.f;
#pragma unroll
    for (int e = 0; e < 8; ++e) { v[e] = expf(v[e] - m); s += v[e]; }
    float inv = 1.f / s;
#pragma unroll
    for (int e = 0; e < 8; ++e) coef[b * 8 + e] = v[e] * inv;
}

extern "C" void kernel_launch(void* const* d_in, const int* in_sizes, int n_in,
                              void* d_out, int out_size, void* d_ws, size_t ws_size,
                              hipStream_t stream) {
    const float* x   = (const float*)d_in[0];
    const float* z   = (const float*)d_in[1];
    const float* gw0 = (const float*)d_in[2];
    const float* gw1 = (const float*)d_in[4];
    const float* gw2 = (const float*)d_in[6];
    const float* gw3 = (const float*)d_in[8];
    const float* gb3 = (const float*)d_in[9];
    const float* gb0 = (const float*)d_in[3];
    const float* gb1 = (const float*)d_in[5];
    const float* gb2 = (const float*)d_in[7];
    const float* w0  = (const float*)d_in[10];
    const float* b0  = (const float*)d_in[11];
    const float* w1  = (const float*)d_in[12];
    const float* b1  = (const float*)d_in[13];
    const float* w2  = (const float*)d_in[14];
    const float* b2  = (const float*)d_in[15];

    // Workspace layout (bytes). Total ~30.2 MB.
    char* p = (char*)d_ws;
    auto take = [&](size_t elems, size_t esz) { char* r = p; p += elems * esz; return r; };
    bf16* A0h = (bf16*)take((size_t)BSZ * 160, 2);
    bf16* A0l = (bf16*)take((size_t)BSZ * 160, 2);
    bf16* Ph  = (bf16*)take((size_t)BSZ * 288, 2);
    bf16* Pl  = (bf16*)take((size_t)BSZ * 288, 2);
    bf16* Qh  = (bf16*)take((size_t)BSZ * 288, 2);
    bf16* Ql  = (bf16*)take((size_t)BSZ * 288, 2);
    bf16* gw0h = (bf16*)take(256 * 160, 2), *gw0l = (bf16*)take(256 * 160, 2);
    bf16* gw1h = (bf16*)take(256 * 256, 2), *gw1l = (bf16*)take(256 * 256, 2);
    bf16* gw2h = (bf16*)take(256 * 256, 2), *gw2l = (bf16*)take(256 * 256, 2);
    bf16* gw3h = (bf16*)take(64 * 256, 2),  *gw3l = (bf16*)take(64 * 256, 2);
    bf16* w0h  = (bf16*)take((size_t)8 * 256 * 160, 2), *w0l = (bf16*)take((size_t)8 * 256 * 160, 2);
    bf16* w1h  = (bf16*)take((size_t)8 * 256 * 288, 2), *w1l = (bf16*)take((size_t)8 * 256 * 288, 2);
    bf16* w2h  = (bf16*)take((size_t)8 * 128 * 288, 2), *w2l = (bf16*)take((size_t)8 * 128 * 288, 2);
    float* logits = (float*)take((size_t)BSZ * 8, 4);
    float* coef   = (float*)take((size_t)BSZ * 8, 4);
    float* out    = (float*)d_out;

    dim3 blk(256);
    // Per-launch preprocessing (ws is re-poisoned before every call).
    conv_inputs<<<dim3(BSZ * 192 / 256), blk, 0, stream>>>(x, z, A0h, A0l, Ph, Pl, Qh, Ql);
    conv_w<<<dim3((1 * 256 * 160 + 255) / 256), blk, 0, stream>>>(gw0, gw0h, gw0l, 1, 160, 256, 256);
    conv_w<<<dim3((1 * 256 * 256 + 255) / 256), blk, 0, stream>>>(gw1, gw1h, gw1l, 1, 256, 256, 256);
    conv_w<<<dim3((1 * 256 * 256 + 255) / 256), blk, 0, stream>>>(gw2, gw2h, gw2l, 1, 256, 256, 256);
    conv_w<<<dim3((1 * 64 * 256 + 255) / 256), blk, 0, stream>>>(gw3, gw3h, gw3l, 1, 256, 8, 64);
    conv_w<<<dim3((8 * 256 * 160 + 255) / 256), blk, 0, stream>>>(w0, w0h, w0l, 8, 160, 256, 256);
    conv_w<<<dim3((8 * 256 * 288 + 255) / 256), blk, 0, stream>>>(w1, w1h, w1l, 8, 288, 256, 256);
    conv_w<<<dim3((8 * 128 * 288 + 255) / 256), blk, 0, stream>>>(w2, w2h, w2l, 8, 288, 128, 128);

    // Gating MLP (EXP=1)
    mfma_moe<1, 0><<<dim3(128, 4), blk, 0, stream>>>(A0h, A0l, 160, gw0h, gw0l, gb0, 256,
                                                     nullptr, 160, 256, Ph, Pl, nullptr, 288);
    mfma_moe<1, 0><<<dim3(128, 4), blk, 0, stream>>>(Ph, Pl, 288, gw1h, gw1l, gb1, 256,
                                                     nullptr, 256, 256, Qh, Ql, nullptr, 288);
    mfma_moe<1, 0><<<dim3(128, 4), blk, 0, stream>>>(Qh, Ql, 288, gw2h, gw2l, gb2, 256,
                                                     nullptr, 256, 256, Ph, Pl, nullptr, 288);
    mfma_moe<1, 1><<<dim3(128, 1), blk, 0, stream>>>(Ph, Pl, 288, gw3h, gw3l, gb3, 8,
                                                     nullptr, 256, 8, nullptr, nullptr, logits, 8);
    softmax8_kernel<<<dim3(BSZ / 256), blk, 0, stream>>>(logits, coef);
    // Expert layers (EXP=8, coef-mixed)
    mfma_moe<8, 0><<<dim3(128, 4), blk, 0, stream>>>(A0h, A0l, 160, w0h, w0l, b0, 256,
                                                     coef, 160, 256, Qh, Ql, nullptr, 288);
    mfma_moe<8, 0><<<dim3(128, 4), blk, 0, stream>>>(Qh, Ql, 288, w1h, w1l, b1, 256,
                                                     coef, 288, 256, Ph, Pl, nullptr, 288);
    mfma_moe<8, 1><<<dim3(128, 2), blk, 0, stream>>>(Ph, Pl, 288, w2h, w2l, b2, 128,
                                                     coef, 288, 128, nullptr, nullptr, out, 128);
}

// Round 4
// 225.189 us; speedup vs baseline: 39.6050x; 1.2257x over previous
//
#include <hip/hip_runtime.h>
#include <hip/hip_bf16.h>

typedef _Float16 half_t;
typedef __attribute__((ext_vector_type(8))) _Float16 half8;
typedef __attribute__((ext_vector_type(4))) _Float16 half4;
typedef __attribute__((ext_vector_type(4))) float float4v;
typedef __attribute__((ext_vector_type(2))) float float2v;
typedef __attribute__((ext_vector_type(4))) unsigned int uint4v;

#define BSZ 8192

// XOR swizzle for packed [row][32] fp16 LDS tiles: logical k-octet k8 (0..3) of
// row r lives at physical column swz(r,k8). b128 reads <=2-way (free), staging
// writes perfectly bank-balanced. Consistent write/read inversion => correct.
__device__ __forceinline__ int swz(int row, int k8) {
    return (k8 ^ ((row + (row >> 2)) & 3)) * 8;
}

// out[64m x 64n block] = act( sum_e coef[b,e]*(A @ W_e) + coef @ bias )
// A: fp16 [B x lda] row-major. W: fp16 [E][Npad][K] (pre-transposed, zero-padded).
// Single-term fp16 MFMA, fp32 accumulate. MODE 0: ELU + fp16 store. MODE 1: fp32 store.
template <int EXP, int MODE>
__global__ __launch_bounds__(256, EXP == 8 ? 3 : 6) void mfma_moe(
    const half_t* __restrict__ A, int lda, const half_t* __restrict__ W,
    const float* __restrict__ bias, int biasN, const float* __restrict__ coef,
    int K, int Nvalid, half_t* __restrict__ Oh, float* __restrict__ Of, int ldo) {
    __shared__ __align__(16) half_t sA[64 * 32];
    __shared__ __align__(16) half_t sB[EXP * 64 * 32];
    __shared__ float sCf[EXP == 8 ? 512 : 8];

    const int tid  = threadIdx.x;
    const int row0 = blockIdx.x * 64;
    const int col0 = blockIdx.y * 64;
    const int Npad = gridDim.y * 64;
    const int lane = tid & 63, wv = tid >> 6;
    const int l15  = lane & 15, quad = lane >> 4;
    const int sm   = tid >> 2;                 // staging row 0..63
    const int su   = tid & 3;                  // staging k-octet
    const int scol = swz(sm, su);              // swizzled LDS column

    if (EXP == 8)  // stage coef tile [64 rows x 8 experts]
        *(float2v*)&sCf[tid * 2] = *(const float2v*)&coef[(size_t)row0 * 8 + tid * 2];

    float4v acc[EXP][4];
#pragma unroll
    for (int e = 0; e < EXP; ++e)
#pragma unroll
        for (int mt = 0; mt < 4; ++mt) acc[e][mt] = (float4v){0.f, 0.f, 0.f, 0.f};

    for (int kc = 0; kc < K; kc += 32) {
        __syncthreads();  // prior chunk's ds_reads drained (and sCf visible)
        *(uint4v*)&sA[sm * 32 + scol] =
            *(const uint4v*)&A[(size_t)(row0 + sm) * lda + kc + su * 8];
#pragma unroll
        for (int e = 0; e < EXP; ++e)
            *(uint4v*)&sB[(e * 64 + sm) * 32 + scol] =
                *(const uint4v*)&W[((size_t)e * Npad + col0 + sm) * K + kc + su * 8];
        __syncthreads();

        // A frags: m = mt*16 + l15, k = quad*8 + j (hoisted across experts)
        half8 a[4];
#pragma unroll
        for (int mt = 0; mt < 4; ++mt) {
            const int m = mt * 16 + l15;
            a[mt] = *(const half8*)&sA[m * 32 + swz(m, quad)];
        }
#pragma unroll
        for (int e = 0; e < EXP; ++e) {
            const int n = wv * 16 + l15;
            half8 b = *(const half8*)&sB[(e * 64 + n) * 32 + swz(n, quad)];
#pragma unroll
            for (int mt = 0; mt < 4; ++mt)
                acc[e][mt] = __builtin_amdgcn_mfma_f32_16x16x32_f16(a[mt], b, acc[e][mt], 0, 0, 0);
        }
    }

    // Epilogue. C/D layout: col = l15, row = quad*4 + r (verified in round 3).
    const int col = col0 + wv * 16 + l15;
    const bool cok = col < Nvalid;
    float bv[EXP];
#pragma unroll
    for (int e = 0; e < EXP; ++e) bv[e] = cok ? bias[e * biasN + col] : 0.f;

#pragma unroll
    for (int mt = 0; mt < 4; ++mt) {
#pragma unroll
        for (int r = 0; r < 4; ++r) {
            const int rl = mt * 16 + quad * 4 + r;
            float val;
            if (EXP == 1) {
                val = acc[0][mt][r] + bv[0];
            } else {
                val = 0.f;
#pragma unroll
                for (int e = 0; e < EXP; ++e) val += sCf[rl * 8 + e] * (acc[e][mt][r] + bv[e]);
            }
            if (cok) {
                const size_t o = (size_t)(row0 + rl) * ldo + col;
                if (MODE == 0) {
                    val = (val > 0.f) ? val : expm1f(val);  // ELU(alpha=1)
                    Oh[o] = (half_t)val;
                } else {
                    Of[o] = val;
                }
            }
        }
    }
}

// Build A0 fp16 [B,160] = concat(x,z); fill z-cols 256..287 of P and Q.
__global__ __launch_bounds__(256) void conv_inputs(
    const float* __restrict__ x, const float* __restrict__ z,
    half_t* __restrict__ A0, half_t* __restrict__ P, half_t* __restrict__ Q) {
    int idx = blockIdx.x * 256 + threadIdx.x;  // BSZ*192
    int b = idx / 192, c = idx % 192;
    float v = (c < 128) ? x[(size_t)b * 128 + c] : z[(size_t)b * 32 + ((c - 128) & 31)];
    half_t h = (half_t)v;
    if (c < 160) {
        A0[(size_t)b * 160 + c] = h;
    } else {
        size_t o = (size_t)b * 288 + 96 + c;  // col 256 + (c-160)
        P[o] = h;
        Q[o] = h;
    }
}

// Fused weight prep: [E][K][N] fp32 -> [E][Npad][K] fp16, LDS-tiled transpose
// (coalesced loads AND stores), zero-padded for n >= N. K % 32 == 0, N % 4 == 0.
struct WDesc { const float* src; half_t* dst; int K, N, Npad, blk0; };
struct WPack { WDesc d[7]; };

__global__ __launch_bounds__(256) void conv_w_all(WPack pk) {
    __shared__ float t[32][33];
    const int bid = blockIdx.x;
    int di = 0;
#pragma unroll
    for (int i = 1; i < 7; ++i)
        if (bid >= pk.d[i].blk0) di = i;
    const WDesc d = pk.d[di];
    const int ntiles = d.Npad / 32, ktiles = d.K / 32;
    int local = bid - d.blk0;
    const int e  = local / (ktiles * ntiles);
    local %= ktiles * ntiles;
    const int k0 = (local / ntiles) * 32, n0 = (local % ntiles) * 32;
    const int tr = threadIdx.x >> 3;        // 0..31
    const int tc = (threadIdx.x & 7) * 4;   // 0,4,..,28

    float4 v = {0.f, 0.f, 0.f, 0.f};
    if (n0 + tc < d.N)  // N%4==0 -> whole quad valid or none
        v = *(const float4*)&d.src[((size_t)e * d.K + k0 + tr) * d.N + n0 + tc];
    t[tr][tc] = v.x; t[tr][tc + 1] = v.y; t[tr][tc + 2] = v.z; t[tr][tc + 3] = v.w;
    __syncthreads();
    half4 h;
#pragma unroll
    for (int i = 0; i < 4; ++i) h[i] = (half_t)t[tc + i][tr];
    *(half4*)&d.dst[((size_t)e * d.Npad + n0 + tr) * d.K + k0 + tc] = h;
}

__global__ __launch_bounds__(256) void softmax8_kernel(const float* __restrict__ logits,
                                                       float* __restrict__ coef) {
    int b = blockIdx.x * 256 + threadIdx.x;
    if (b >= BSZ) return;
    float v[8], m = -1e30f;
#pragma unroll
    for (int e = 0; e < 8; ++e) { v[e] = logits[b * 8 + e]; m = fmaxf(m, v[e]); }
    float s = 0.f;
#pragma unroll
    for (int e = 0; e < 8; ++e) { v[e] = expf(v[e] - m); s += v[e]; }
    float inv = 1.f / s;
#pragma unroll
    for (int e = 0; e < 8; ++e) coef[b * 8 + e] = v[e] * inv;
}

extern "C" void kernel_launch(void* const* d_in, const int* in_sizes, int n_in,
                              void* d_out, int out_size, void* d_ws, size_t ws_size,
                              hipStream_t stream) {
    const float* x   = (const float*)d_in[0];
    const float* z   = (const float*)d_in[1];
    const float* gw0 = (const float*)d_in[2];
    const float* gb0 = (const float*)d_in[3];
    const float* gw1 = (const float*)d_in[4];
    const float* gb1 = (const float*)d_in[5];
    const float* gw2 = (const float*)d_in[6];
    const float* gb2 = (const float*)d_in[7];
    const float* gw3 = (const float*)d_in[8];
    const float* gb3 = (const float*)d_in[9];
    const float* w0  = (const float*)d_in[10];
    const float* b0  = (const float*)d_in[11];
    const float* w1  = (const float*)d_in[12];
    const float* b1  = (const float*)d_in[13];
    const float* w2  = (const float*)d_in[14];
    const float* b2  = (const float*)d_in[15];

    char* p = (char*)d_ws;
    auto take = [&](size_t bytes) { char* r = p; p += bytes; return r; };
    half_t* A0  = (half_t*)take((size_t)BSZ * 160 * 2);
    half_t* P   = (half_t*)take((size_t)BSZ * 288 * 2);
    half_t* Q   = (half_t*)take((size_t)BSZ * 288 * 2);
    half_t* Wg0 = (half_t*)take((size_t)256 * 160 * 2);
    half_t* Wg1 = (half_t*)take((size_t)256 * 256 * 2);
    half_t* Wg2 = (half_t*)take((size_t)256 * 256 * 2);
    half_t* Wg3 = (half_t*)take((size_t)64 * 256 * 2);
    half_t* W0  = (half_t*)take((size_t)8 * 256 * 160 * 2);
    half_t* W1  = (half_t*)take((size_t)8 * 256 * 288 * 2);
    half_t* W2  = (half_t*)take((size_t)8 * 128 * 288 * 2);
    float* logits = (float*)take((size_t)BSZ * 8 * 4);
    float* coef   = (float*)take((size_t)BSZ * 8 * 4);
    float* out    = (float*)d_out;

    // Fused weight-prep descriptor table (blk0 = prefix of tile counts).
    WPack pk;
    int blk = 0;
    auto mk = [&](int i, const float* s, half_t* dst, int K, int N, int Npad, int E) {
        pk.d[i] = WDesc{s, dst, K, N, Npad, blk};
        blk += E * (K / 32) * (Npad / 32);
    };
    mk(0, gw0, Wg0, 160, 256, 256, 1);
    mk(1, gw1, Wg1, 256, 256, 256, 1);
    mk(2, gw2, Wg2, 256, 256, 256, 1);
    mk(3, gw3, Wg3, 256, 8, 64, 1);
    mk(4, w0, W0, 160, 256, 256, 8);
    mk(5, w1, W1, 288, 256, 256, 8);
    mk(6, w2, W2, 288, 128, 128, 8);

    dim3 b256(256);
    conv_inputs<<<dim3(BSZ * 192 / 256), b256, 0, stream>>>(x, z, A0, P, Q);
    conv_w_all<<<dim3(blk), b256, 0, stream>>>(pk);

    // Gating MLP (EXP=1)
    mfma_moe<1, 0><<<dim3(128, 4), b256, 0, stream>>>(A0, 160, Wg0, gb0, 256, nullptr,
                                                      160, 256, P, nullptr, 288);
    mfma_moe<1, 0><<<dim3(128, 4), b256, 0, stream>>>(P, 288, Wg1, gb1, 256, nullptr,
                                                      256, 256, Q, nullptr, 288);
    mfma_moe<1, 0><<<dim3(128, 4), b256, 0, stream>>>(Q, 288, Wg2, gb2, 256, nullptr,
                                                      256, 256, P, nullptr, 288);
    mfma_moe<1, 1><<<dim3(128, 1), b256, 0, stream>>>(P, 288, Wg3, gb3, 8, nullptr,
                                                      256, 8, nullptr, logits, 8);
    softmax8_kernel<<<dim3(BSZ / 256), b256, 0, stream>>>(logits, coef);
    // Expert layers (EXP=8, coef-mixed)
    mfma_moe<8, 0><<<dim3(128, 4), b256, 0, stream>>>(A0, 160, W0, b0, 256, coef,
                                                      160, 256, Q, nullptr, 288);
    mfma_moe<8, 0><<<dim3(128, 4), b256, 0, stream>>>(Q, 288, W1, b1, 256, coef,
                                                      288, 256, P, nullptr, 288);
    mfma_moe<8, 1><<<dim3(128, 2), b256, 0, stream>>>(P, 288, W2, b2, 128, coef,
                                                      288, 128, nullptr, out, 128);
}

// Round 5
// 159.843 us; speedup vs baseline: 55.7957x; 1.4088x over previous
//
#include <hip/hip_runtime.h>
#include <hip/hip_bf16.h>

typedef _Float16 half_t;
typedef __attribute__((ext_vector_type(8))) _Float16 half8;
typedef __attribute__((ext_vector_type(4))) _Float16 half4;
typedef __attribute__((ext_vector_type(4))) float float4v;
typedef __attribute__((ext_vector_type(4))) unsigned int uint4v;

#define BSZ 8192

// Block tile: M=128 (4 waves x 32 rows, mt=2 frags) x N=16.
// A: fp16 [B x lda], fragments loaded DIRECTLY global->register (no LDS, no barrier dep).
// W: fp16 [E][Npad][K] pre-transposed; per-chunk B (8 KB for E=8) staged in LDS,
// shared by all 4 waves. Single-term fp16 MFMA (verified layout from rounds 3/4),
// fp32 accumulate, coef-mixed epilogue.
// MODE 0: ELU + fp16 store. MODE 1: plain fp32 store.
template <int EXP, int MODE>
__global__ __launch_bounds__(256, 4) void moe_gemm2(
    const half_t* __restrict__ A, int lda, const half_t* __restrict__ W, int Npad,
    const float* __restrict__ bias, int biasN, const float* __restrict__ coef,
    int K, int Nvalid, half_t* __restrict__ Oh, float* __restrict__ Of, int ldo) {
    // B chunk: 16B units indexed s = e*64 + n*4 + koct  (EXP*64 units)
    __shared__ __align__(16) half_t sB[EXP * 64 * 8];
    __shared__ float sCf[EXP == 8 ? 128 * 8 : 8];

    const int tid  = threadIdx.x;
    const int row0 = blockIdx.x * 128;
    const int col0 = blockIdx.y * 16;
    const int lane = tid & 63, wv = tid >> 6;
    const int l15  = lane & 15, quad = lane >> 4;

    // Staging assignment: thread t stages units 2t, 2t+1 (32B contiguous of one W row).
    const bool sact = (EXP == 8) || (tid < 32);
    const int se = (EXP == 8) ? (tid >> 5) : 0;
    const int sn = (tid >> 1) & 15;
    const int sp = (tid & 1) * 2;
    const half_t* wsrc = &W[((size_t)se * Npad + col0 + sn) * K + sp * 8];
    half_t* wdst = &sB[(se * 64 + sn * 4 + sp) * 8];

    if (EXP == 8)  // coef tile for this block's 128 rows: 4 KB, 16B/thread
        *(uint4v*)&sCf[tid * 4] = *(const uint4v*)&coef[(size_t)row0 * 8 + tid * 4];

    float4v acc[EXP][2];
#pragma unroll
    for (int e = 0; e < EXP; ++e)
#pragma unroll
        for (int mt = 0; mt < 2; ++mt) acc[e][mt] = (float4v){0.f, 0.f, 0.f, 0.f};

    for (int kc = 0; kc < K; kc += 32) {
        // A frags straight from global (L2-hot): m = wv*32 + mt*16 + l15, k = quad*8+j
        half8 a[2];
#pragma unroll
        for (int mt = 0; mt < 2; ++mt)
            a[mt] = *(const half8*)&A[(size_t)(row0 + wv * 32 + mt * 16 + l15) * lda +
                                      kc + quad * 8];
        __syncthreads();  // prior chunk's sB reads complete
        if (sact) {
            *(uint4v*)wdst       = *(const uint4v*)&wsrc[kc];
            *(uint4v*)&wdst[8]   = *(const uint4v*)&wsrc[kc + 8];
        }
        __syncthreads();
#pragma unroll
        for (int e = 0; e < EXP; ++e) {
            half8 b = *(const half8*)&sB[(e * 64 + l15 * 4 + quad) * 8];
#pragma unroll
            for (int mt = 0; mt < 2; ++mt)
                acc[e][mt] = __builtin_amdgcn_mfma_f32_16x16x32_f16(a[mt], b, acc[e][mt], 0, 0, 0);
        }
    }

    // Epilogue. C/D: col = l15, row = quad*4 + r (within 16x16 frag), wave rows wv*32.
    const int col = col0 + l15;
    const bool cok = col < Nvalid;
    float bv[EXP];
#pragma unroll
    for (int e = 0; e < EXP; ++e) bv[e] = cok ? bias[e * biasN + col] : 0.f;

#pragma unroll
    for (int mt = 0; mt < 2; ++mt) {
#pragma unroll
        for (int r = 0; r < 4; ++r) {
            const int rl = wv * 32 + mt * 16 + quad * 4 + r;
            float val;
            if (EXP == 1) {
                val = acc[0][mt][r] + bv[0];
            } else {
                const float4v c0 = *(const float4v*)&sCf[rl * 8];
                const float4v c1 = *(const float4v*)&sCf[rl * 8 + 4];
                val = 0.f;
#pragma unroll
                for (int e = 0; e < 4; ++e) val += c0[e] * (acc[e][mt][r] + bv[e]);
#pragma unroll
                for (int e = 4; e < 8; ++e) val += c1[e - 4] * (acc[e][mt][r] + bv[e]);
            }
            if (cok) {
                const size_t o = (size_t)(row0 + rl) * ldo + col;
                if (MODE == 0) {
                    val = (val > 0.f) ? val : expm1f(val);  // ELU(alpha=1)
                    Oh[o] = (half_t)val;
                } else {
                    Of[o] = val;
                }
            }
        }
    }
}

// Build A0 fp16 [B,160] = concat(x,z); fill z-cols 256..287 of P and Q.
__global__ __launch_bounds__(256) void conv_inputs(
    const float* __restrict__ x, const float* __restrict__ z,
    half_t* __restrict__ A0, half_t* __restrict__ P, half_t* __restrict__ Q) {
    int idx = blockIdx.x * 256 + threadIdx.x;  // BSZ*192
    int b = idx / 192, c = idx % 192;
    float v = (c < 128) ? x[(size_t)b * 128 + c] : z[(size_t)b * 32 + ((c - 128) & 31)];
    half_t h = (half_t)v;
    if (c < 160) {
        A0[(size_t)b * 160 + c] = h;
    } else {
        size_t o = (size_t)b * 288 + 96 + c;  // col 256 + (c-160)
        P[o] = h;
        Q[o] = h;
    }
}

// Fused weight prep: [E][K][N] fp32 -> [E][Npad][K] fp16, LDS-tiled transpose,
// zero-padded for n >= N. K % 32 == 0, Npad % 32 == 0, N % 4 == 0.
struct WDesc { const float* src; half_t* dst; int K, N, Npad, blk0; };
struct WPack { WDesc d[7]; };

__global__ __launch_bounds__(256) void conv_w_all(WPack pk) {
    __shared__ float t[32][33];
    const int bid = blockIdx.x;
    int di = 0;
#pragma unroll
    for (int i = 1; i < 7; ++i)
        if (bid >= pk.d[i].blk0) di = i;
    const WDesc d = pk.d[di];
    const int ntiles = d.Npad / 32, ktiles = d.K / 32;
    int local = bid - d.blk0;
    const int e  = local / (ktiles * ntiles);
    local %= ktiles * ntiles;
    const int k0 = (local / ntiles) * 32, n0 = (local % ntiles) * 32;
    const int tr = threadIdx.x >> 3;        // 0..31
    const int tc = (threadIdx.x & 7) * 4;   // 0,4,..,28

    float4 v = {0.f, 0.f, 0.f, 0.f};
    if (n0 + tc < d.N)
        v = *(const float4*)&d.src[((size_t)e * d.K + k0 + tr) * d.N + n0 + tc];
    t[tr][tc] = v.x; t[tr][tc + 1] = v.y; t[tr][tc + 2] = v.z; t[tr][tc + 3] = v.w;
    __syncthreads();
    half4 h;
#pragma unroll
    for (int i = 0; i < 4; ++i) h[i] = (half_t)t[tc + i][tr];
    *(half4*)&d.dst[((size_t)e * d.Npad + n0 + tr) * d.K + k0 + tc] = h;
}

__global__ __launch_bounds__(256) void softmax8_kernel(const float* __restrict__ logits,
                                                       float* __restrict__ coef) {
    int b = blockIdx.x * 256 + threadIdx.x;
    if (b >= BSZ) return;
    float v[8], m = -1e30f;
#pragma unroll
    for (int e = 0; e < 8; ++e) { v[e] = logits[b * 8 + e]; m = fmaxf(m, v[e]); }
    float s = 0.f;
#pragma unroll
    for (int e = 0; e < 8; ++e) { v[e] = expf(v[e] - m); s += v[e]; }
    float inv = 1.f / s;
#pragma unroll
    for (int e = 0; e < 8; ++e) coef[b * 8 + e] = v[e] * inv;
}

extern "C" void kernel_launch(void* const* d_in, const int* in_sizes, int n_in,
                              void* d_out, int out_size, void* d_ws, size_t ws_size,
                              hipStream_t stream) {
    const float* x   = (const float*)d_in[0];
    const float* z   = (const float*)d_in[1];
    const float* gw0 = (const float*)d_in[2];
    const float* gb0 = (const float*)d_in[3];
    const float* gw1 = (const float*)d_in[4];
    const float* gb1 = (const float*)d_in[5];
    const float* gw2 = (const float*)d_in[6];
    const float* gb2 = (const float*)d_in[7];
    const float* gw3 = (const float*)d_in[8];
    const float* gb3 = (const float*)d_in[9];
    const float* w0  = (const float*)d_in[10];
    const float* b0  = (const float*)d_in[11];
    const float* w1  = (const float*)d_in[12];
    const float* b1  = (const float*)d_in[13];
    const float* w2  = (const float*)d_in[14];
    const float* b2  = (const float*)d_in[15];

    char* p = (char*)d_ws;
    auto take = [&](size_t bytes) { char* r = p; p += bytes; return r; };
    half_t* A0  = (half_t*)take((size_t)BSZ * 160 * 2);
    half_t* P   = (half_t*)take((size_t)BSZ * 288 * 2);
    half_t* Q   = (half_t*)take((size_t)BSZ * 288 * 2);
    half_t* Wg0 = (half_t*)take((size_t)256 * 160 * 2);
    half_t* Wg1 = (half_t*)take((size_t)256 * 256 * 2);
    half_t* Wg2 = (half_t*)take((size_t)256 * 256 * 2);
    half_t* Wg3 = (half_t*)take((size_t)32 * 256 * 2);
    half_t* W0  = (half_t*)take((size_t)8 * 256 * 160 * 2);
    half_t* W1  = (half_t*)take((size_t)8 * 256 * 288 * 2);
    half_t* W2  = (half_t*)take((size_t)8 * 128 * 288 * 2);
    float* logits = (float*)take((size_t)BSZ * 8 * 4);
    float* coef   = (float*)take((size_t)BSZ * 8 * 4);
    float* out    = (float*)d_out;

    WPack pk;
    int blk = 0;
    auto mk = [&](int i, const float* s, half_t* dst, int K, int N, int Npad, int E) {
        pk.d[i] = WDesc{s, dst, K, N, Npad, blk};
        blk += E * (K / 32) * (Npad / 32);
    };
    mk(0, gw0, Wg0, 160, 256, 256, 1);
    mk(1, gw1, Wg1, 256, 256, 256, 1);
    mk(2, gw2, Wg2, 256, 256, 256, 1);
    mk(3, gw3, Wg3, 256, 8, 32, 1);
    mk(4, w0, W0, 160, 256, 256, 8);
    mk(5, w1, W1, 288, 256, 256, 8);
    mk(6, w2, W2, 288, 128, 128, 8);

    dim3 b256(256);
    conv_inputs<<<dim3(BSZ * 192 / 256), b256, 0, stream>>>(x, z, A0, P, Q);
    conv_w_all<<<dim3(blk), b256, 0, stream>>>(pk);

    // Gating MLP (EXP=1); block tile 128x16
    moe_gemm2<1, 0><<<dim3(64, 16), b256, 0, stream>>>(A0, 160, Wg0, 256, gb0, 256,
                                                       nullptr, 160, 256, P, nullptr, 288);
    moe_gemm2<1, 0><<<dim3(64, 16), b256, 0, stream>>>(P, 288, Wg1, 256, gb1, 256,
                                                       nullptr, 256, 256, Q, nullptr, 288);
    moe_gemm2<1, 0><<<dim3(64, 16), b256, 0, stream>>>(Q, 288, Wg2, 256, gb2, 256,
                                                       nullptr, 256, 256, P, nullptr, 288);
    moe_gemm2<1, 1><<<dim3(64, 1), b256, 0, stream>>>(P, 288, Wg3, 32, gb3, 8,
                                                      nullptr, 256, 8, nullptr, logits, 8);
    softmax8_kernel<<<dim3(BSZ / 256), b256, 0, stream>>>(logits, coef);
    // Expert layers (EXP=8, coef-mixed)
    moe_gemm2<8, 0><<<dim3(64, 16), b256, 0, stream>>>(A0, 160, W0, 256, b0, 256,
                                                       coef, 160, 256, Q, nullptr, 288);
    moe_gemm2<8, 0><<<dim3(64, 16), b256, 0, stream>>>(Q, 288, W1, 256, b1, 256,
                                                       coef, 288, 256, P, nullptr, 288);
    moe_gemm2<8, 1><<<dim3(64, 8), b256, 0, stream>>>(P, 288, W2, 128, b2, 128,
                                                      coef, 288, 128, nullptr, out, 128);
}